// Round 5
// baseline (430.880 us; speedup 1.0000x reference)
//
#include <hip/hip_runtime.h>
#include <stdint.h>

// out[b][o] = clamp((sum_k x[b][k]*W[o][k] + t[o]) >> (-n[o]), act_min[o], act_max[o])
// B=8192, IN=4096, OUT=4096. x,W arrive int32; harness reads d_out as int32.
//
// R5: 256x256 block, 8 waves, wave tile 128x64 (fragment intensity 85 ops/B vs 64),
// BK=64, single-buffer LDS with compute-hides-prefetch K-loop:
//   ds_read all frags -> barrier -> issue global_load_lds(k+1) -> 32 MFMAs -> barrier.

#define BDIM 8192
#define INDIM 4096
#define OUTDIM 4096

typedef __attribute__((ext_vector_type(4))) int I4;

// ---------------- pack: int32 -> int8, coalesced, 4 int4/thread ----------------
__global__ __launch_bounds__(256) void pack_both(const int* __restrict__ x,
                                                 const int* __restrict__ W,
                                                 uint32_t* __restrict__ dst) {
    const uint32_t xq = (uint32_t)BDIM * (INDIM / 4);   // 8388608 int4s in x
    uint32_t base = blockIdx.x * 1024;                  // block never straddles x/W
    const int4* src4 = (base < xq) ? ((const int4*)x + base)
                                   : ((const int4*)W + (base - xq));
#pragma unroll
    for (int q = 0; q < 4; ++q) {
        uint32_t off = threadIdx.x + q * 256;
        int4 a = src4[off];
        dst[base + off] = ((uint32_t)a.x & 255u)
                        | (((uint32_t)a.y & 255u) << 8)
                        | (((uint32_t)a.z & 255u) << 16)
                        | (((uint32_t)a.w & 255u) << 24);
    }
}

// ---------------- GEMM ----------------
__global__ __launch_bounds__(512, 2) void gemm_i8_fused(
    const uint8_t* __restrict__ Xp,   // [BDIM][INDIM] int8
    const uint8_t* __restrict__ Wp,   // [OUTDIM][INDIM] int8
    const int* __restrict__ t, const int* __restrict__ nsh,
    const int* __restrict__ amin, const int* __restrict__ amax,
    int* __restrict__ out) {

    __shared__ uint8_t sA[256 * 64];  // 16 KB
    __shared__ uint8_t sB[256 * 64];  // 16 KB

    const int bn = blockIdx.x;            // 0..15
    const int bm = blockIdx.y;            // 0..31
    const int tid = threadIdx.x;
    const int w = tid >> 6;               // 0..7
    const int lane = tid & 63;
    const int wrow = (w >> 2) * 128;      // wave tile 128x64
    const int wcol = (w & 3) * 64;
    const int quad = lane >> 4;
    const int rl = lane & 15;

    // staging geometry: chunk = 1 KB = 16 rows x 64 B; wave w stages chunks 2w,2w+1
    const int lrow = lane >> 2;           // 0..15
    const int lcol = (lane & 3) * 16;

    const uint8_t* gA = Xp + (size_t)(bm * 256) * INDIM;
    const uint8_t* gB = Wp + (size_t)(bn * 256) * INDIM;
    const int c0 = 2 * w, c1 = 2 * w + 1;
    const uint8_t* gA0 = gA + (size_t)(c0 * 16 + lrow) * INDIM + lcol;
    const uint8_t* gA1 = gA + (size_t)(c1 * 16 + lrow) * INDIM + lcol;
    const uint8_t* gB0 = gB + (size_t)(c0 * 16 + lrow) * INDIM + lcol;
    const uint8_t* gB1 = gB + (size_t)(c1 * 16 + lrow) * INDIM + lcol;
    __attribute__((address_space(3))) uint32_t* dA0 =
        (__attribute__((address_space(3))) uint32_t*)(sA + c0 * 1024 + lane * 16);
    __attribute__((address_space(3))) uint32_t* dA1 =
        (__attribute__((address_space(3))) uint32_t*)(sA + c1 * 1024 + lane * 16);
    __attribute__((address_space(3))) uint32_t* dB0 =
        (__attribute__((address_space(3))) uint32_t*)(sB + c0 * 1024 + lane * 16);
    __attribute__((address_space(3))) uint32_t* dB1 =
        (__attribute__((address_space(3))) uint32_t*)(sB + c1 * 1024 + lane * 16);

    // prologue: stage tile 0
    __builtin_amdgcn_global_load_lds((const __attribute__((address_space(1))) uint32_t*)gA0, dA0, 16, 0, 0);
    __builtin_amdgcn_global_load_lds((const __attribute__((address_space(1))) uint32_t*)gA1, dA1, 16, 0, 0);
    __builtin_amdgcn_global_load_lds((const __attribute__((address_space(1))) uint32_t*)gB0, dB0, 16, 0, 0);
    __builtin_amdgcn_global_load_lds((const __attribute__((address_space(1))) uint32_t*)gB1, dB1, 16, 0, 0);
    __syncthreads();

    I4 acc[8][4];
#pragma unroll
    for (int i = 0; i < 8; ++i)
#pragma unroll
        for (int j = 0; j < 4; ++j) acc[i][j] = (I4){0, 0, 0, 0};

    for (int it = 0; it < 64; ++it) {
        // 1. all fragments for this tile -> registers (12 x ds_read_b128)
        I4 af[8], bf[4];
#pragma unroll
        for (int i = 0; i < 8; ++i)
            af[i] = *(const I4*)(sA + (wrow + i * 16 + rl) * 64 + quad * 16);
#pragma unroll
        for (int j = 0; j < 4; ++j)
            bf[j] = *(const I4*)(sB + (wcol + j * 16 + rl) * 64 + quad * 16);

        __syncthreads();   // all waves done reading LDS (lgkm drained)

        // 2. issue async staging of next tile into the SAME buffers
        if (it < 63) {
            const size_t ko = (size_t)(it + 1) * 64;
            __builtin_amdgcn_global_load_lds((const __attribute__((address_space(1))) uint32_t*)(gA0 + ko), dA0, 16, 0, 0);
            __builtin_amdgcn_global_load_lds((const __attribute__((address_space(1))) uint32_t*)(gA1 + ko), dA1, 16, 0, 0);
            __builtin_amdgcn_global_load_lds((const __attribute__((address_space(1))) uint32_t*)(gB0 + ko), dB0, 16, 0, 0);
            __builtin_amdgcn_global_load_lds((const __attribute__((address_space(1))) uint32_t*)(gB1 + ko), dB1, 16, 0, 0);
        }

        // 3. 32 MFMAs (~650 cyc of issue) cover the in-flight loads
#pragma unroll
        for (int i = 0; i < 8; ++i)
#pragma unroll
            for (int j = 0; j < 4; ++j)
                acc[i][j] = __builtin_amdgcn_mfma_i32_16x16x64_i8(af[i], bf[j], acc[i][j], 0, 0, 0);

        __syncthreads();   // drain: loads long since complete
    }

    // epilogue: C/D layout col=lane&15, row=(lane>>4)*4+reg (verified R2)
#pragma unroll
    for (int j = 0; j < 4; ++j) {
        const int o = bn * 256 + wcol + j * 16 + rl;
        const int tt = t[o];
        const int sh = -nsh[o];
        const int mn = amin[o];
        const int mx = amax[o];
#pragma unroll
        for (int i = 0; i < 8; ++i) {
            const int rowbase = bm * 256 + wrow + i * 16 + quad * 4;
#pragma unroll
            for (int r = 0; r < 4; ++r) {
                int v = acc[i][j][r] + tt;
                v >>= sh;
                v = v < mn ? mn : (v > mx ? mx : v);
                __builtin_nontemporal_store(v, &out[(size_t)(rowbase + r) * OUTDIM + o]);
            }
        }
    }
}

extern "C" void kernel_launch(void* const* d_in, const int* in_sizes, int n_in,
                              void* d_out, int out_size, void* d_ws, size_t ws_size,
                              hipStream_t stream) {
    const int* x = (const int*)d_in[0];
    const int* W = (const int*)d_in[1];
    const int* t = (const int*)d_in[2];
    const int* n = (const int*)d_in[3];
    const int* amin = (const int*)d_in[4];
    const int* amax = (const int*)d_in[5];
    int* out = (int*)d_out;

    uint8_t* xp = (uint8_t*)d_ws;                    // 33554432 B
    uint8_t* wp = xp + (size_t)BDIM * INDIM;         // 16777216 B

    {
        // (8192+4096)*4096/4 int4s / 1024 per block = 12288 blocks
        int nblocks = ((BDIM + OUTDIM) * (INDIM / 4)) / 1024;
        pack_both<<<nblocks, 256, 0, stream>>>(x, W, (uint32_t*)d_ws);
    }

    dim3 grid(OUTDIM / 256, BDIM / 256);  // (16, 32) = 512 blocks
    gemm_i8_fused<<<grid, 512, 0, stream>>>(xp, wp, t, n, amin, amax, out);
}

// Round 6
// 407.797 us; speedup vs baseline: 1.0566x; 1.0566x over previous
//
#include <hip/hip_runtime.h>
#include <stdint.h>

// out[b][o] = clamp((sum_k x[b][k]*W[o][k] + t[o]) >> (-n[o]), act_min[o], act_max[o])
// B=8192, IN=4096, OUT=4096. x,W arrive int32; harness reads d_out as int32.
//
// R6: flat (no-LDS) GEMM on mfma_i32_32x32x32_i8, wave tile 128x64 (4x2 grid of
// 32x32), register double-buffered fragment loads straight from global in
// fragment order (85 ops/loaded-byte vs 64 in R4).

#define BDIM 8192
#define INDIM 4096
#define OUTDIM 4096

typedef __attribute__((ext_vector_type(4))) int I4;
typedef __attribute__((ext_vector_type(16))) int I16;

// ---------------- pack: int32 -> int8 in 32x32 fragment order ----------------
// tile = 32 rows; kb = 32-byte K-block (128 per row); lane layout:
//   row = tile*32 + (lane&31), k-bytes [(lane>>5)*16, +16) within kb block.
// dst[((tile*128 + kb)*64 + lane)*16 + b]; tile stride = 1<<17 bytes.
__global__ __launch_bounds__(256) void pack_frag32(const int* __restrict__ x,
                                                   const int* __restrict__ W,
                                                   uint32_t* __restrict__ xp,
                                                   uint32_t* __restrict__ wp) {
    const uint32_t xq = (BDIM / 32) * 128 * 64;   // 2097152
    uint32_t u = blockIdx.x * 256 + threadIdx.x;
    const int* src;
    uint32_t* dst;
    if (u < xq) {
        uint32_t m32 = u >> 13, kb = (u >> 6) & 127, lane = u & 63;
        src = x + (size_t)(m32 * 32 + (lane & 31)) * INDIM + kb * 32 + (lane >> 5) * 16;
        dst = xp + (size_t)u * 4;
    } else {
        uint32_t v = u - xq;
        uint32_t n32 = v >> 13, kb = (v >> 6) & 127, lane = v & 63;
        src = W + (size_t)(n32 * 32 + (lane & 31)) * INDIM + kb * 32 + (lane >> 5) * 16;
        dst = wp + (size_t)v * 4;
    }
    uint32_t ow[4];
#pragma unroll
    for (int q = 0; q < 4; ++q) {
        int4 a = ((const int4*)src)[q];
        ow[q] = ((uint32_t)a.x & 255u)
              | (((uint32_t)a.y & 255u) << 8)
              | (((uint32_t)a.z & 255u) << 16)
              | (((uint32_t)a.w & 255u) << 24);
    }
    *(uint4*)dst = *(uint4*)ow;
}

// ---------------- flat GEMM: block 256x128, 4 waves, wave 128x64 ----------------
__global__ __launch_bounds__(256, 2) void gemm_flat32(
    const uint8_t* __restrict__ Xp,   // fragment-ordered
    const uint8_t* __restrict__ Wp,   // fragment-ordered
    const int* __restrict__ t, const int* __restrict__ nsh,
    const int* __restrict__ amin, const int* __restrict__ amax,
    int* __restrict__ out) {

    const int bm = blockIdx.x;            // 0..31 (batch tiles of 256)
    const int bn = blockIdx.y;            // 0..31 (OUT tiles of 128)
    const int tid = threadIdx.x;
    const int w = tid >> 6;               // 0..3
    const int lane = tid & 63;
    const int wr = w >> 1;                // wave row half (128)
    const int wc = w & 1;                 // wave col half (64)

    const uint8_t* pa[4];
    const uint8_t* pb[2];
#pragma unroll
    for (int i = 0; i < 4; ++i)
        pa[i] = Xp + ((size_t)(bm * 8 + wr * 4 + i) << 17) + lane * 16;
#pragma unroll
    for (int j = 0; j < 2; ++j)
        pb[j] = Wp + ((size_t)(bn * 4 + wc * 2 + j) << 17) + lane * 16;

    I16 acc[4][2];
#pragma unroll
    for (int i = 0; i < 4; ++i)
#pragma unroll
        for (int j = 0; j < 2; ++j)
#pragma unroll
            for (int r = 0; r < 16; ++r) acc[i][j][r] = 0;

    I4 a0[4], b0[2], a1[4], b1[2];
#pragma unroll
    for (int i = 0; i < 4; ++i) a0[i] = *(const I4*)(pa[i]);
#pragma unroll
    for (int j = 0; j < 2; ++j) b0[j] = *(const I4*)(pb[j]);
#pragma unroll
    for (int i = 0; i < 4; ++i) a1[i] = *(const I4*)(pa[i] + 1024);
#pragma unroll
    for (int j = 0; j < 2; ++j) b1[j] = *(const I4*)(pb[j] + 1024);

    for (int kb = 0; kb < 126; kb += 2) {
#pragma unroll
        for (int i = 0; i < 4; ++i)
#pragma unroll
            for (int j = 0; j < 2; ++j)
                acc[i][j] = __builtin_amdgcn_mfma_i32_32x32x32_i8(a0[i], b0[j], acc[i][j], 0, 0, 0);
        const size_t o0 = (size_t)(kb + 2) * 1024;
#pragma unroll
        for (int i = 0; i < 4; ++i) a0[i] = *(const I4*)(pa[i] + o0);
#pragma unroll
        for (int j = 0; j < 2; ++j) b0[j] = *(const I4*)(pb[j] + o0);

#pragma unroll
        for (int i = 0; i < 4; ++i)
#pragma unroll
            for (int j = 0; j < 2; ++j)
                acc[i][j] = __builtin_amdgcn_mfma_i32_32x32x32_i8(a1[i], b1[j], acc[i][j], 0, 0, 0);
        const size_t o1 = (size_t)(kb + 3) * 1024;
#pragma unroll
        for (int i = 0; i < 4; ++i) a1[i] = *(const I4*)(pa[i] + o1);
#pragma unroll
        for (int j = 0; j < 2; ++j) b1[j] = *(const I4*)(pb[j] + o1);

        // phase-lock block waves for L1 temporal sharing (no memory drain)
        __builtin_amdgcn_s_barrier();
    }
#pragma unroll
    for (int i = 0; i < 4; ++i)
#pragma unroll
        for (int j = 0; j < 2; ++j)
            acc[i][j] = __builtin_amdgcn_mfma_i32_32x32x32_i8(a0[i], b0[j], acc[i][j], 0, 0, 0);
#pragma unroll
    for (int i = 0; i < 4; ++i)
#pragma unroll
        for (int j = 0; j < 2; ++j)
            acc[i][j] = __builtin_amdgcn_mfma_i32_32x32x32_i8(a1[i], b1[j], acc[i][j], 0, 0, 0);

    // epilogue: 32x32 C/D layout col=lane&31, row=(reg&3)+8*(reg>>2)+4*(lane>>5)
    // (verified m74/m101; dtype-independent m121/m127)
#pragma unroll
    for (int j = 0; j < 2; ++j) {
        const int o = bn * 128 + wc * 64 + j * 32 + (lane & 31);
        const int tt = t[o];
        const int sh = -nsh[o];
        const int mn = amin[o];
        const int mx = amax[o];
#pragma unroll
        for (int i = 0; i < 4; ++i) {
            const int rowbase = bm * 256 + wr * 128 + i * 32 + 4 * (lane >> 5);
#pragma unroll
            for (int r = 0; r < 16; ++r) {
                const int row = rowbase + (r & 3) + 8 * (r >> 2);
                int v = acc[i][j][r] + tt;
                v >>= sh;
                v = v < mn ? mn : (v > mx ? mx : v);
                __builtin_nontemporal_store(v, &out[(size_t)row * OUTDIM + o]);
            }
        }
    }
}

extern "C" void kernel_launch(void* const* d_in, const int* in_sizes, int n_in,
                              void* d_out, int out_size, void* d_ws, size_t ws_size,
                              hipStream_t stream) {
    const int* x = (const int*)d_in[0];
    const int* W = (const int*)d_in[1];
    const int* t = (const int*)d_in[2];
    const int* n = (const int*)d_in[3];
    const int* amin = (const int*)d_in[4];
    const int* amax = (const int*)d_in[5];
    int* out = (int*)d_out;

    uint8_t* xp = (uint8_t*)d_ws;                    // 33554432 B (fragment order)
    uint8_t* wp = xp + (size_t)BDIM * INDIM;         // 16777216 B (fragment order)

    {
        int nthreads = (BDIM / 32) * 128 * 64 + (OUTDIM / 32) * 128 * 64;  // 3145728
        pack_frag32<<<nthreads / 256, 256, 0, stream>>>(x, W, (uint32_t*)xp, (uint32_t*)wp);
    }

    dim3 grid(BDIM / 256, OUTDIM / 128);  // (32, 32) — bm fastest for L2 bn-clustering
    gemm_flat32<<<grid, 256, 0, stream>>>(xp, wp, t, n, amin, amax, out);
}